// Round 9
// baseline (176.457 us; speedup 1.0000x reference)
//
#include <hip/hip_runtime.h>
#include <hip/hip_bf16.h>
#include <math.h>

// Problem constants
constexpr int Bc = 2;
constexpr int Sc = 2048;
constexpr int E  = 1024;
constexpr int Hn = 16;
constexpr int Dh = 64;

typedef short bf16x8 __attribute__((ext_vector_type(8)));   // 8 bf16 = 4 VGPRs
typedef float f32x4  __attribute__((ext_vector_type(4)));

#define MFMA16(a, b, c) __builtin_amdgcn_mfma_f32_16x16x32_bf16((a), (b), (c), 0, 0, 0)

// Q is pre-scaled by 1/sqrt(64) * log2(e) so attention uses exp2 directly.
constexpr float QSCALE = 0.125f * 1.4426950408889634f;
constexpr float FIXED_M2 = 18.0f;   // fixed softmax "max" in exp2 units (~12.5 sigma)

__device__ inline bf16x8 load8(const __hip_bfloat16* p) {
    return *reinterpret_cast<const bf16x8*>(p);
}

// packed f32x2 -> bf16x2 (v_cvt_pk_bf16_f32 on gfx950)
__device__ inline ushort4 pack4(float a, float b, float c, float d) {
    __hip_bfloat162 lo = __float22bfloat162_rn(make_float2(a, b));
    __hip_bfloat162 hi = __float22bfloat162_rn(make_float2(c, d));
    ushort4 u;
    __builtin_memcpy(&u.x, &lo, 4);
    __builtin_memcpy(&u.z, &hi, 4);
    return u;
}

// 8 consecutive fp32 -> bf16x8 (register-side convert, packed cvt)
__device__ inline bf16x8 cvt8(const float* p) {
    float4 a = *reinterpret_cast<const float4*>(p);
    float4 b = *reinterpret_cast<const float4*>(p + 4);
    ushort4 lo = pack4(a.x, a.y, a.z, a.w);
    ushort4 hi = pack4(b.x, b.y, b.z, b.w);
    bf16x8 r;
    __builtin_memcpy(&r, &lo, 8);
    __builtin_memcpy(reinterpret_cast<char*>(&r) + 8, &hi, 8);
    return r;
}

__device__ inline float fast_exp2(float x) {
#if __has_builtin(__builtin_amdgcn_exp2f)
    return __builtin_amdgcn_exp2f(x);
#else
    return exp2f(x);
#endif
}

// ===========================================================================
// Fragment-order layouts (lane = quad*16 + l16, 8 bf16 per lane):
//  Qf[bh][t=0..127][half][lane][8]  : Q[t*16+l16][half*32+quad*8+j] * QSCALE
//  Kf[bh][kt][nt][half][lane][8]    : K[kt*64+nt*16+l16][half*32+quad*8+j]
//  Vf[bh][kt][nt][half][lane][8]    : V[key=kt*64+half*32+quad*8+j][nt*16+l16]
//  Af[rt=0..255][kk=0..31][lane][8] : att[rt*16+l16][kk*32+quad*8+j]
//  Wf[ct=0..63][kk][lane][8]        : Wo[ct*16+l16][kk*32+quad*8+j]
// All hot-loop loads are contiguous 1KB wave-bursts.
// ===========================================================================

// ---------------------------------------------------------------------------
// Kernel 1: per-head QKV projection (fp32 in, bf16 fragment-order out) +
// merged Wo->Wf reorder (blocks >= 1024; Wf is consumed only by out_proj,
// two launches later, so stream order guarantees completion — saves the
// separate cvt_w dispatch).
// Wq/Wk/Wv fragments are converted fp32->bf16 directly in registers (cvt8
// with cvt_w's exact address math) — no Wf3 staging buffer, no dependency.
// Grid 1536 x 256: blocks 0..1023 projection, 1024..1535 Wo reorder.
// ---------------------------------------------------------------------------
__global__ __launch_bounds__(256) void qkv_proj(
    const float* __restrict__ vals,
    const float* __restrict__ keys,
    const float* __restrict__ quer,
    const float* __restrict__ Wq,
    const float* __restrict__ Wk,
    const float* __restrict__ Wv,
    const float* __restrict__ Wo,
    __hip_bfloat16* __restrict__ Qf,
    __hip_bfloat16* __restrict__ Kf,
    __hip_bfloat16* __restrict__ Vf,
    __hip_bfloat16* __restrict__ Wf)
{
    // stride 72 bf16 (=144B): 2-way bank alias only (free per m136)
    __shared__ __align__(16) __hip_bfloat16 X[3][64 * 72];

    const int bid = blockIdx.x;
    if (bid >= 1024) {               // ---- merged Wo -> Wf reorder (cvt_w body)
        const int i = (bid - 1024) * 256 + threadIdx.x;   // < 131072 exactly
        const int l16 = i & 15, quad = (i >> 4) & 3;
        const int kk = (i >> 6) & 31, ct = i >> 11;
        bf16x8 v = cvt8(Wo + (size_t)(ct * 16 + l16) * E + kk * 32 + quad * 8);
        *reinterpret_cast<bf16x8*>(Wf + (size_t)i * 8) = v;
        return;
    }

    const int st  = bid & 31;          // s-tile (S/64 = 32)
    const int h   = (bid >> 5) & 15;
    const int b   = bid >> 9;
    const int sbase = st * 64;
    const int tid = threadIdx.x;

    const float* srcs[3] = { quer, keys, vals };
#pragma unroll
    for (int m = 0; m < 3; ++m) {
        for (int i = tid; i < 512; i += 256) {   // 64 rows x 8 chunks of 8 floats
            const int r = i >> 3, c = i & 7;
            bf16x8 v = cvt8(srcs[m] + (size_t)(b * Sc + sbase + r) * E + h * 64 + c * 8);
            *reinterpret_cast<bf16x8*>(&X[m][r * 72 + c * 8]) = v;
        }
    }
    __syncthreads();

    const int lane = tid & 63, w = tid >> 6;
    const int quad = lane >> 4, l16 = lane & 15;
    const int bh = b * Hn + h;
    const size_t bhoff = (size_t)bh * 131072;   // per-bh elems in Qf/Kf/Vf

    // ---- Q and K: transposed orientation. C[i=d][j=token]. ----
#pragma unroll
    for (int m = 0; m < 2; ++m) {
        // B-frag: X rows w*16 + l16 (token dim)
        bf16x8 xb0 = load8(&X[m][(w * 16 + l16) * 72 + quad * 8]);
        bf16x8 xb1 = load8(&X[m][(w * 16 + l16) * 72 + quad * 8 + 32]);
        const float* Wm = (m == 0) ? Wq : Wk;
#pragma unroll
        for (int ntd = 0; ntd < 4; ++ntd) {
            // A-frag: W rows ntd*16 + l16 (output-d dim), converted in-register
            bf16x8 wa0 = cvt8(Wm + (ntd * 16 + l16) * 64 + quad * 8);
            bf16x8 wa1 = cvt8(Wm + (ntd * 16 + l16) * 64 + 32 + quad * 8);
            f32x4 acc = (f32x4){0.f, 0.f, 0.f, 0.f};
            acc = MFMA16(wa0, xb0, acc);
            acc = MFMA16(wa1, xb1, acc);
            // lane holds token = (w*16 + l16), d = ntd*16 + quad*4 + r
            const int half   = ntd >> 1;
            const int quad_f = (ntd & 1) * 2 + (quad >> 1);
            const int j0     = (quad & 1) * 4;
            if (m == 0) {
                const int t = st * 4 + w;          // 16-row q-tile index
                *reinterpret_cast<ushort4*>(
                    Qf + bhoff + ((size_t)(t * 2 + half) * 64 + quad_f * 16 + l16) * 8 + j0) =
                    pack4(acc[0] * QSCALE, acc[1] * QSCALE, acc[2] * QSCALE, acc[3] * QSCALE);
            } else {
                *reinterpret_cast<ushort4*>(
                    Kf + bhoff + (((size_t)(st * 4 + w) * 2 + half) * 64 + quad_f * 16 + l16) * 8 + j0) =
                    pack4(acc[0], acc[1], acc[2], acc[3]);
            }
        }
    }

    // ---- V: normal orientation. C[i=key][j=d]. lane: 4 consecutive keys. ----
    {
        bf16x8 xa0 = load8(&X[2][(w * 16 + l16) * 72 + quad * 8]);
        bf16x8 xa1 = load8(&X[2][(w * 16 + l16) * 72 + quad * 8 + 32]);
        const int half   = w >> 1;
        const int quad_f = (w & 1) * 2 + (quad >> 1);
        const int j0     = (quad & 1) * 4;
#pragma unroll
        for (int nt = 0; nt < 4; ++nt) {
            bf16x8 wb0 = cvt8(Wv + (nt * 16 + l16) * 64 + quad * 8);
            bf16x8 wb1 = cvt8(Wv + (nt * 16 + l16) * 64 + 32 + quad * 8);
            f32x4 acc = (f32x4){0.f, 0.f, 0.f, 0.f};
            acc = MFMA16(xa0, wb0, acc);
            acc = MFMA16(xa1, wb1, acc);
            // lane holds key = w*16 + quad*4 + r (within kt=st), d = nt*16 + l16
            *reinterpret_cast<ushort4*>(
                Vf + bhoff + (((size_t)(st * 4 + nt) * 2 + half) * 64 + quad_f * 16 + l16) * 8 + j0) =
                pack4(acc[0], acc[1], acc[2], acc[3]);
        }
    }
}

// ---------------------------------------------------------------------------
// Kernel 2: causal flash attention — transposed-S, fragment-order K/V/Q.
// (Verified-best R3 structure: 32-row q-blocks, 2 adjacent 16-row tiles share
// one K/V register load; V(kt) at loop top, K(kt+2) prefetched into separate
// registers so scores cover all load latency. 2-wave blocks = split-K parity.)
// Grid: 2048 blocks = 64 u x 32 bh (bh minor: same-head blocks share an XCD;
// u descending so long blocks launch first).
// ---------------------------------------------------------------------------
__global__ __launch_bounds__(128, 2) void flash_attn(
    const __hip_bfloat16* __restrict__ Qf,
    const __hip_bfloat16* __restrict__ Kf,
    const __hip_bfloat16* __restrict__ Vf,
    __hip_bfloat16* __restrict__ Af)
{
    __shared__ __align__(16) __hip_bfloat16 P[2][2][16 * 72];  // [wave][tile][q=16][key=64+pad]
    __shared__ __align__(16) float OB[2][16 * 68];             // per-tile partial O (hf=1)
    __shared__ float LB[2][16];

    const int bid = blockIdx.x;
    const int bh = bid & 31;           // XCD-sticky head index
    const int u  = 63 - (bid >> 5);    // 32-row q-block, big first
    const int h  = bh & 15;
    const int b  = bh >> 4;
    const int tid = threadIdx.x, lane = tid & 63, hf = tid >> 6;  // hf = split-K parity
    const int quad = lane >> 4, l16 = lane & 15;
    const int t0 = 2 * u, t1 = 2 * u + 1;
    const int nk = (u >> 1) + 1;       // same for t0 and t1

    const __hip_bfloat16* Qp = Qf + (size_t)bh * 131072;
    const __hip_bfloat16* Kp = Kf + (size_t)bh * 131072;
    const __hip_bfloat16* Vp = Vf + (size_t)bh * 131072;

    // all-ones A-fragment for row-sum MFMA
    bf16x8 onesf;
#pragma unroll
    for (int q = 0; q < 8; ++q) onesf[q] = (short)0x3F80;

    // Q fragments for both tiles: contiguous 1KB bursts
    const bf16x8 q0a = load8(Qp + ((size_t)(t0 * 2 + 0) * 64 + lane) * 8);
    const bf16x8 q0b = load8(Qp + ((size_t)(t0 * 2 + 1) * 64 + lane) * 8);
    const bf16x8 q1a = load8(Qp + ((size_t)(t1 * 2 + 0) * 64 + lane) * 8);
    const bf16x8 q1b = load8(Qp + ((size_t)(t1 * 2 + 1) * 64 + lane) * 8);

    f32x4 oa0[4], oa1[4];
#pragma unroll
    for (int nt = 0; nt < 4; ++nt) {
        oa0[nt] = (f32x4){0.f, 0.f, 0.f, 0.f};
        oa1[nt] = (f32x4){0.f, 0.f, 0.f, 0.f};
    }
    f32x4 ls0 = (f32x4){0.f, 0.f, 0.f, 0.f};
    f32x4 ls1 = (f32x4){0.f, 0.f, 0.f, 0.f};

    // ---- preload first owned K tile (in-bounds even when hf >= nk)
    bf16x8 ka[4], kb[4];
#pragma unroll
    for (int nt = 0; nt < 4; ++nt) {
        const size_t o = (((size_t)hf * 4 + nt) * 2) * 512;
        ka[nt] = load8(Kp + o + lane * 8);
        kb[nt] = load8(Kp + o + 512 + lane * 8);
    }

    for (int kt = hf; kt < nk; kt += 2) {
        // ---- V(kt) loads issued first: latency covered by both score passes
        bf16x8 va[4], vb[4];
#pragma unroll
        for (int nt = 0; nt < 4; ++nt) {
            const size_t o = (((size_t)kt * 4 + nt) * 2) * 512;
            va[nt] = load8(Vp + o + lane * 8);
            vb[nt] = load8(Vp + o + 512 + lane * 8);
        }
        // ---- K(kt+2) prefetch (redundant reload on last iter)
        const int nkt = (kt + 2 < nk) ? kt + 2 : kt;
        bf16x8 na[4], nb[4];
#pragma unroll
        for (int nt = 0; nt < 4; ++nt) {
            const size_t o = (((size_t)nkt * 4 + nt) * 2) * 512;
            na[nt] = load8(Kp + o + lane * 8);
            nb[nt] = load8(Kp + o + 512 + lane * 8);
        }

        const int kbase = kt * 64;
        const bool diag = (kt == nk - 1);

        // ---- tile 0: S^T = K·Q^T with -M2 folded into the accumulator init
        f32x4 sc[4];
#pragma unroll
        for (int ntk = 0; ntk < 4; ++ntk) {
            f32x4 z = (f32x4){-FIXED_M2, -FIXED_M2, -FIXED_M2, -FIXED_M2};
            z = MFMA16(ka[ntk], q0a, z);
            z = MFMA16(kb[ntk], q0b, z);
            sc[ntk] = z;
        }
        if (diag) {
            const int qrow = t0 * 16 + l16;
#pragma unroll
            for (int ntk = 0; ntk < 4; ++ntk)
#pragma unroll
                for (int r = 0; r < 4; ++r)
                    if (kbase + ntk * 16 + quad * 4 + r > qrow) sc[ntk][r] = -1e30f;
        }
#pragma unroll
        for (int ntk = 0; ntk < 4; ++ntk) {
            *reinterpret_cast<ushort4*>(&P[hf][0][l16 * 72 + ntk * 16 + quad * 4]) =
                pack4(fast_exp2(sc[ntk][0]), fast_exp2(sc[ntk][1]),
                      fast_exp2(sc[ntk][2]), fast_exp2(sc[ntk][3]));
        }

        // ---- tile 1 scores (last use of ka/kb)
#pragma unroll
        for (int ntk = 0; ntk < 4; ++ntk) {
            f32x4 z = (f32x4){-FIXED_M2, -FIXED_M2, -FIXED_M2, -FIXED_M2};
            z = MFMA16(ka[ntk], q1a, z);
            z = MFMA16(kb[ntk], q1b, z);
            sc[ntk] = z;
        }
        if (diag) {
            const int qrow = t1 * 16 + l16;
#pragma unroll
            for (int ntk = 0; ntk < 4; ++ntk)
#pragma unroll
                for (int r = 0; r < 4; ++r)
                    if (kbase + ntk * 16 + quad * 4 + r > qrow) sc[ntk][r] = -1e30f;
        }
#pragma unroll
        for (int ntk = 0; ntk < 4; ++ntk) {
            *reinterpret_cast<ushort4*>(&P[hf][1][l16 * 72 + ntk * 16 + quad * 4]) =
                pack4(fast_exp2(sc[ntk][0]), fast_exp2(sc[ntk][1]),
                      fast_exp2(sc[ntk][2]), fast_exp2(sc[ntk][3]));
        }

        // ---- PV tile 0: O^T += Vt · P^T ; row sums via ones-MFMA
        {
            bf16x8 pf0 = load8(&P[hf][0][l16 * 72 + quad * 8]);
            bf16x8 pf1 = load8(&P[hf][0][l16 * 72 + quad * 8 + 32]);
#pragma unroll
            for (int nt = 0; nt < 4; ++nt) {
                oa0[nt] = MFMA16(va[nt], pf0, oa0[nt]);
                oa0[nt] = MFMA16(vb[nt], pf1, oa0[nt]);
            }
            ls0 = MFMA16(onesf, pf0, ls0);
            ls0 = MFMA16(onesf, pf1, ls0);
        }
        // ---- PV tile 1
        {
            bf16x8 pf0 = load8(&P[hf][1][l16 * 72 + quad * 8]);
            bf16x8 pf1 = load8(&P[hf][1][l16 * 72 + quad * 8 + 32]);
#pragma unroll
            for (int nt = 0; nt < 4; ++nt) {
                oa1[nt] = MFMA16(va[nt], pf0, oa1[nt]);
                oa1[nt] = MFMA16(vb[nt], pf1, oa1[nt]);
            }
            ls1 = MFMA16(onesf, pf0, ls1);
            ls1 = MFMA16(onesf, pf1, ls1);
        }

        // ---- rotate K prefetch into place
#pragma unroll
        for (int nt = 0; nt < 4; ++nt) { ka[nt] = na[nt]; kb[nt] = nb[nt]; }
    }

    // ---- split-K combine across the 2 waves
    if (hf == 1) {
#pragma unroll
        for (int nt = 0; nt < 4; ++nt) {
            *reinterpret_cast<float4*>(&OB[0][l16 * 68 + nt * 16 + quad * 4]) =
                (float4){ oa0[nt][0], oa0[nt][1], oa0[nt][2], oa0[nt][3] };
            *reinterpret_cast<float4*>(&OB[1][l16 * 68 + nt * 16 + quad * 4]) =
                (float4){ oa1[nt][0], oa1[nt][1], oa1[nt][2], oa1[nt][3] };
        }
        if (quad == 0) { LB[0][l16] = ls0[0]; LB[1][l16] = ls1[0]; }
    }
    __syncthreads();
    if (hf == 0) {
#pragma unroll
        for (int tl = 0; tl < 2; ++tl) {
            const float lsw = (tl == 0) ? ls0[0] : ls1[0];
            const float inv = 1.0f / (lsw + LB[tl][l16]);
            const int rt = b * 128 + (tl == 0 ? t0 : t1);
#pragma unroll
            for (int nt = 0; nt < 4; ++nt) {
                float4 ob = *reinterpret_cast<float4*>(&OB[tl][l16 * 68 + nt * 16 + quad * 4]);
                const f32x4 ov = (tl == 0) ? oa0[nt] : oa1[nt];
                // e = h*64 + nt*16 + quad*4 + r  ->  A-frag order for out_proj
                const int kk     = h * 2 + (nt >> 1);
                const int quad_f = (nt & 1) * 2 + (quad >> 1);
                const int j0     = (quad & 1) * 4;
                *reinterpret_cast<ushort4*>(
                    Af + (((size_t)rt * 32 + kk) * 64 + quad_f * 16 + l16) * 8 + j0) =
                    pack4((ov[0] + ob.x) * inv, (ov[1] + ob.y) * inv,
                          (ov[2] + ob.z) * inv, (ov[3] + ob.w) * inv);
            }
        }
    }
}

// ---------------------------------------------------------------------------
// Kernel 3: out = att @ Wo.T + bo (fp32 out). Fragment-order A (Af) and B
// (Wf). 128x64 tile, prefetch depth 2 (12 loads in flight — verified best;
// depth 4 regressed, R5/R6). XCD-locality swizzle (neutral but free, R8).
// ---------------------------------------------------------------------------
__global__ __launch_bounds__(256) void out_proj(
    const __hip_bfloat16* __restrict__ Af,  // [rt][kk][lane][8]
    const __hip_bfloat16* __restrict__ Wf,  // [ct][kk][lane][8]
    const float* __restrict__ bo,           // [E] fp32
    float* __restrict__ out)                // [B*S, E] fp32
{
    const int bid = blockIdx.x;
    const int xcd = bid & 7;                // dispatch round-robins bid%8 -> XCD
    const int j   = bid >> 3;               // 0..63
    const int rb  = xcd * 4 + (j & 3);      // row block 0..31 (4096/128)
    const int cb  = j >> 2;                 // col tile 0..15 (E/64)
    const int tid = threadIdx.x, lane = tid & 63, w = tid >> 6;
    const int quad = lane >> 4, l16 = lane & 15;
    const int rt0 = rb * 8 + w;     // 16-row tiles; second at +4
    const int cbase = cb * 64;

    const __hip_bfloat16* pa0 = Af + ((size_t)rt0 * 32) * 512 + lane * 8;
    const __hip_bfloat16* pa1 = pa0 + 4 * 32 * 512;
    const __hip_bfloat16* pw  = Wf + ((size_t)cb * 4 * 32) * 512 + lane * 8;

    f32x4 acc[2][4];
#pragma unroll
    for (int u = 0; u < 2; ++u)
#pragma unroll
        for (int nt = 0; nt < 4; ++nt) acc[u][nt] = (f32x4){0.f, 0.f, 0.f, 0.f};

    // two fragment sets in flight (prefetch depth 2)
    bf16x8 af0[2], af1[2], bf[4][2];
#pragma unroll
    for (int s = 0; s < 2; ++s) {
        const size_t ko = (size_t)s * 512;
        af0[s] = load8(pa0 + ko);
        af1[s] = load8(pa1 + ko);
#pragma unroll
        for (int nt = 0; nt < 4; ++nt) bf[nt][s] = load8(pw + (size_t)nt * 32 * 512 + ko);
    }

    for (int kk = 0; kk < 32; kk += 2) {
#pragma unroll
        for (int s = 0; s < 2; ++s) {
            const int kn = kk + 2 + s;
            const size_t ko = (size_t)((kn < 32) ? kn : kk + s) * 512;
            bf16x8 naf0 = load8(pa0 + ko), naf1 = load8(pa1 + ko);
            bf16x8 nbf[4];
#pragma unroll
            for (int nt = 0; nt < 4; ++nt) nbf[nt] = load8(pw + (size_t)nt * 32 * 512 + ko);
#pragma unroll
            for (int nt = 0; nt < 4; ++nt) {
                acc[0][nt] = MFMA16(af0[s], bf[nt][s], acc[0][nt]);
                acc[1][nt] = MFMA16(af1[s], bf[nt][s], acc[1][nt]);
            }
            af0[s] = naf0; af1[s] = naf1;
#pragma unroll
            for (int nt = 0; nt < 4; ++nt) bf[nt][s] = nbf[nt];
        }
    }
#pragma unroll
    for (int nt = 0; nt < 4; ++nt) {
        const float bv = bo[cbase + nt * 16 + l16];
#pragma unroll
        for (int u = 0; u < 2; ++u)
#pragma unroll
            for (int r = 0; r < 4; ++r) {
                const int row = (rt0 + u * 4) * 16 + quad * 4 + r;
                out[(size_t)row * E + cbase + nt * 16 + l16] = acc[u][nt][r] + bv;
            }
    }
}

// ---------------------------------------------------------------------------
extern "C" void kernel_launch(void* const* d_in, const int* in_sizes, int n_in,
                              void* d_out, int out_size, void* d_ws, size_t ws_size,
                              hipStream_t stream) {
    const float* vals = (const float*)d_in[0];
    const float* keys = (const float*)d_in[1];
    const float* quer = (const float*)d_in[2];
    // d_in[3] = causal mask (bool): recomputed from indices, unused
    const float* Wv = (const float*)d_in[4];
    const float* Wk = (const float*)d_in[5];
    const float* Wq = (const float*)d_in[6];
    const float* Wo = (const float*)d_in[7];
    const float* bo = (const float*)d_in[8];
    float* out = (float*)d_out;

    __hip_bfloat16* ws = (__hip_bfloat16*)d_ws;
    constexpr size_t NTOK = (size_t)Bc * Hn * Sc * Dh;  // 4194304
    __hip_bfloat16* Qw  = ws;                 // 8 MB, fragment order
    __hip_bfloat16* Kw  = ws + NTOK;          // 8 MB, fragment order
    __hip_bfloat16* Vw  = ws + 2 * NTOK;      // 8 MB, fragment order
    __hip_bfloat16* Aw  = ws + 3 * NTOK;      // 8 MB, fragment order
    __hip_bfloat16* Wof = ws + 4 * NTOK;      // 2 MB, fragment order

    hipLaunchKernelGGL(qkv_proj, dim3(1536), dim3(256), 0, stream,
                       vals, keys, quer, Wq, Wk, Wv, Wo, Qw, Kw, Vw, Wof);
    hipLaunchKernelGGL(flash_attn, dim3(64 * 32), dim3(128), 0, stream,
                       Qw, Kw, Vw, Aw);
    hipLaunchKernelGGL(out_proj, dim3(32 * 16), dim3(256), 0, stream,
                       Aw, Wof, bo, out);
}

// Round 10
// 161.017 us; speedup vs baseline: 1.0959x; 1.0959x over previous
//
#include <hip/hip_runtime.h>
#include <hip/hip_bf16.h>
#include <math.h>

// Problem constants
constexpr int Bc = 2;
constexpr int Sc = 2048;
constexpr int E  = 1024;
constexpr int Hn = 16;
constexpr int Dh = 64;

typedef short bf16x8 __attribute__((ext_vector_type(8)));   // 8 bf16 = 4 VGPRs
typedef float f32x4  __attribute__((ext_vector_type(4)));

#define MFMA16(a, b, c) __builtin_amdgcn_mfma_f32_16x16x32_bf16((a), (b), (c), 0, 0, 0)

// Q is pre-scaled by 1/sqrt(64) * log2(e) so attention uses exp2 directly.
constexpr float QSCALE = 0.125f * 1.4426950408889634f;
constexpr float FIXED_M2 = 18.0f;   // fixed softmax "max" in exp2 units (~12.5 sigma)

__device__ inline bf16x8 load8(const __hip_bfloat16* p) {
    return *reinterpret_cast<const bf16x8*>(p);
}

// packed f32x2 -> bf16x2 (v_cvt_pk_bf16_f32 on gfx950)
__device__ inline ushort4 pack4(float a, float b, float c, float d) {
    __hip_bfloat162 lo = __float22bfloat162_rn(make_float2(a, b));
    __hip_bfloat162 hi = __float22bfloat162_rn(make_float2(c, d));
    ushort4 u;
    __builtin_memcpy(&u.x, &lo, 4);
    __builtin_memcpy(&u.z, &hi, 4);
    return u;
}

// 8 consecutive fp32 -> bf16x8 (register-side convert, packed cvt)
__device__ inline bf16x8 cvt8(const float* p) {
    float4 a = *reinterpret_cast<const float4*>(p);
    float4 b = *reinterpret_cast<const float4*>(p + 4);
    ushort4 lo = pack4(a.x, a.y, a.z, a.w);
    ushort4 hi = pack4(b.x, b.y, b.z, b.w);
    bf16x8 r;
    __builtin_memcpy(&r, &lo, 8);
    __builtin_memcpy(reinterpret_cast<char*>(&r) + 8, &hi, 8);
    return r;
}

__device__ inline float fast_exp2(float x) {
#if __has_builtin(__builtin_amdgcn_exp2f)
    return __builtin_amdgcn_exp2f(x);
#else
    return exp2f(x);
#endif
}

// ===========================================================================
// Fragment-order layouts (lane = quad*16 + l16, 8 bf16 per lane):
//  Qf[bh][t=0..127][half][lane][8]  : Q[t*16+l16][half*32+quad*8+j] * QSCALE
//  Kf[bh][kt][nt][half][lane][8]    : K[kt*64+nt*16+l16][half*32+quad*8+j]
//  Vf[bh][kt][nt][half][lane][8]    : V[key=kt*64+half*32+quad*8+j][nt*16+l16]
//  Af[rt=0..255][kk=0..31][lane][8] : att[rt*16+l16][kk*32+quad*8+j]
//  Wf[ct=0..63][kk][lane][8]        : Wo[ct*16+l16][kk*32+quad*8+j]
//  Wf3[m][nt*2+half][lane][8]       : Wm[(nt*16+l16)*64 + half*32+quad*8+j]
// All hot-loop loads are contiguous 1KB wave-bursts.
// R9 lesson: merging cvt_w into qkv_proj (in-register W cvt, no Wf3) blew
// qkv_proj up to 42µs latency-bound — keep the separate tiny cvt_w dispatch.
// ===========================================================================

// ---------------------------------------------------------------------------
// Kernel 0: weight reorder. i < 131072: Wo -> Wf. Remainder: Wq/Wk/Wv -> Wf3.
// Grid 518 blocks x 256 = 132608 threads exactly.
// ---------------------------------------------------------------------------
__global__ __launch_bounds__(256) void cvt_w(
    const float* __restrict__ Wo, const float* __restrict__ Wq,
    const float* __restrict__ Wk, const float* __restrict__ Wv,
    __hip_bfloat16* __restrict__ Wf, __hip_bfloat16* __restrict__ Wf3) {
    const int i = blockIdx.x * 256 + threadIdx.x;
    if (i < 131072) {
        const int l16 = i & 15, quad = (i >> 4) & 3;
        const int kk = (i >> 6) & 31, ct = i >> 11;
        bf16x8 v = cvt8(Wo + (size_t)(ct * 16 + l16) * E + kk * 32 + quad * 8);
        *reinterpret_cast<bf16x8*>(Wf + (size_t)i * 8) = v;
    } else {
        const int idx = i - 131072;   // < 1536
        const int m = idx >> 9, r = idx & 511;
        const int lane = r & 63, nh = r >> 6;       // nt*2 + half
        const int nt = nh >> 1, half = nh & 1;
        const int quad = lane >> 4, l16 = lane & 15;
        const float* Wm = (m == 0) ? Wq : (m == 1) ? Wk : Wv;
        bf16x8 v = cvt8(Wm + (nt * 16 + l16) * 64 + half * 32 + quad * 8);
        *reinterpret_cast<bf16x8*>(Wf3 + (size_t)idx * 8) = v;
    }
}

// ---------------------------------------------------------------------------
// Kernel 1: per-head QKV projection (fp32 in, bf16 fragment-order out).
//  Q,K transposed orientation (W as A-operand); V normal. W fragments come
//  pre-converted from Wf3 (contiguous load8).
// ---------------------------------------------------------------------------
__global__ __launch_bounds__(256) void qkv_proj(
    const float* __restrict__ vals,
    const float* __restrict__ keys,
    const float* __restrict__ quer,
    const __hip_bfloat16* __restrict__ Wf3,
    __hip_bfloat16* __restrict__ Qf,
    __hip_bfloat16* __restrict__ Kf,
    __hip_bfloat16* __restrict__ Vf)
{
    // stride 72 bf16 (=144B): 2-way bank alias only (free per m136)
    __shared__ __align__(16) __hip_bfloat16 X[3][64 * 72];

    const int bid = blockIdx.x;
    const int st  = bid & 31;          // s-tile (S/64 = 32)
    const int h   = (bid >> 5) & 15;
    const int b   = bid >> 9;
    const int sbase = st * 64;
    const int tid = threadIdx.x;

    const float* srcs[3] = { quer, keys, vals };
#pragma unroll
    for (int m = 0; m < 3; ++m) {
        for (int i = tid; i < 512; i += 256) {   // 64 rows x 8 chunks of 8 floats
            const int r = i >> 3, c = i & 7;
            bf16x8 v = cvt8(srcs[m] + (size_t)(b * Sc + sbase + r) * E + h * 64 + c * 8);
            *reinterpret_cast<bf16x8*>(&X[m][r * 72 + c * 8]) = v;
        }
    }
    __syncthreads();

    const int lane = tid & 63, w = tid >> 6;
    const int quad = lane >> 4, l16 = lane & 15;
    const int bh = b * Hn + h;
    const size_t bhoff = (size_t)bh * 131072;   // per-bh elems in Qf/Kf/Vf

    // ---- Q and K: transposed orientation. C[i=d][j=token]. ----
#pragma unroll
    for (int m = 0; m < 2; ++m) {
        // B-frag: X rows w*16 + l16 (token dim)
        bf16x8 xb0 = load8(&X[m][(w * 16 + l16) * 72 + quad * 8]);
        bf16x8 xb1 = load8(&X[m][(w * 16 + l16) * 72 + quad * 8 + 32]);
#pragma unroll
        for (int ntd = 0; ntd < 4; ++ntd) {
            // A-frag: W rows ntd*16 + l16 (output-d dim), pre-converted
            bf16x8 wa0 = load8(Wf3 + ((size_t)(m * 8 + ntd * 2 + 0) * 64 + lane) * 8);
            bf16x8 wa1 = load8(Wf3 + ((size_t)(m * 8 + ntd * 2 + 1) * 64 + lane) * 8);
            f32x4 acc = (f32x4){0.f, 0.f, 0.f, 0.f};
            acc = MFMA16(wa0, xb0, acc);
            acc = MFMA16(wa1, xb1, acc);
            // lane holds token = (w*16 + l16), d = ntd*16 + quad*4 + r
            const int half   = ntd >> 1;
            const int quad_f = (ntd & 1) * 2 + (quad >> 1);
            const int j0     = (quad & 1) * 4;
            if (m == 0) {
                const int t = st * 4 + w;          // 16-row q-tile index
                *reinterpret_cast<ushort4*>(
                    Qf + bhoff + ((size_t)(t * 2 + half) * 64 + quad_f * 16 + l16) * 8 + j0) =
                    pack4(acc[0] * QSCALE, acc[1] * QSCALE, acc[2] * QSCALE, acc[3] * QSCALE);
            } else {
                *reinterpret_cast<ushort4*>(
                    Kf + bhoff + (((size_t)(st * 4 + w) * 2 + half) * 64 + quad_f * 16 + l16) * 8 + j0) =
                    pack4(acc[0], acc[1], acc[2], acc[3]);
            }
        }
    }

    // ---- V: normal orientation. C[i=key][j=d]. lane: 4 consecutive keys. ----
    {
        bf16x8 xa0 = load8(&X[2][(w * 16 + l16) * 72 + quad * 8]);
        bf16x8 xa1 = load8(&X[2][(w * 16 + l16) * 72 + quad * 8 + 32]);
        const int half   = w >> 1;
        const int quad_f = (w & 1) * 2 + (quad >> 1);
        const int j0     = (quad & 1) * 4;
#pragma unroll
        for (int nt = 0; nt < 4; ++nt) {
            bf16x8 wb0 = load8(Wf3 + ((size_t)(16 + nt * 2 + 0) * 64 + lane) * 8);
            bf16x8 wb1 = load8(Wf3 + ((size_t)(16 + nt * 2 + 1) * 64 + lane) * 8);
            f32x4 acc = (f32x4){0.f, 0.f, 0.f, 0.f};
            acc = MFMA16(xa0, wb0, acc);
            acc = MFMA16(xa1, wb1, acc);
            // lane holds key = w*16 + quad*4 + r (within kt=st), d = nt*16 + l16
            *reinterpret_cast<ushort4*>(
                Vf + bhoff + (((size_t)(st * 4 + nt) * 2 + half) * 64 + quad_f * 16 + l16) * 8 + j0) =
                pack4(acc[0], acc[1], acc[2], acc[3]);
        }
    }
}

// ---------------------------------------------------------------------------
// Kernel 2: causal flash attention — transposed-S, fragment-order K/V/Q.
// (Verified-best R3 structure: 32-row q-blocks, 2 adjacent 16-row tiles share
// one K/V register load; V(kt) at loop top, K(kt+2) prefetched into separate
// registers so scores cover all load latency. 2-wave blocks = split-K parity.)
// Grid: 2048 blocks = 64 u x 32 bh (bh minor: same-head blocks share an XCD;
// u descending so long blocks launch first).
// ---------------------------------------------------------------------------
__global__ __launch_bounds__(128, 2) void flash_attn(
    const __hip_bfloat16* __restrict__ Qf,
    const __hip_bfloat16* __restrict__ Kf,
    const __hip_bfloat16* __restrict__ Vf,
    __hip_bfloat16* __restrict__ Af)
{
    __shared__ __align__(16) __hip_bfloat16 P[2][2][16 * 72];  // [wave][tile][q=16][key=64+pad]
    __shared__ __align__(16) float OB[2][16 * 68];             // per-tile partial O (hf=1)
    __shared__ float LB[2][16];

    const int bid = blockIdx.x;
    const int bh = bid & 31;           // XCD-sticky head index
    const int u  = 63 - (bid >> 5);    // 32-row q-block, big first
    const int h  = bh & 15;
    const int b  = bh >> 4;
    const int tid = threadIdx.x, lane = tid & 63, hf = tid >> 6;  // hf = split-K parity
    const int quad = lane >> 4, l16 = lane & 15;
    const int t0 = 2 * u, t1 = 2 * u + 1;
    const int nk = (u >> 1) + 1;       // same for t0 and t1

    const __hip_bfloat16* Qp = Qf + (size_t)bh * 131072;
    const __hip_bfloat16* Kp = Kf + (size_t)bh * 131072;
    const __hip_bfloat16* Vp = Vf + (size_t)bh * 131072;

    // all-ones A-fragment for row-sum MFMA
    bf16x8 onesf;
#pragma unroll
    for (int q = 0; q < 8; ++q) onesf[q] = (short)0x3F80;

    // Q fragments for both tiles: contiguous 1KB bursts
    const bf16x8 q0a = load8(Qp + ((size_t)(t0 * 2 + 0) * 64 + lane) * 8);
    const bf16x8 q0b = load8(Qp + ((size_t)(t0 * 2 + 1) * 64 + lane) * 8);
    const bf16x8 q1a = load8(Qp + ((size_t)(t1 * 2 + 0) * 64 + lane) * 8);
    const bf16x8 q1b = load8(Qp + ((size_t)(t1 * 2 + 1) * 64 + lane) * 8);

    f32x4 oa0[4], oa1[4];
#pragma unroll
    for (int nt = 0; nt < 4; ++nt) {
        oa0[nt] = (f32x4){0.f, 0.f, 0.f, 0.f};
        oa1[nt] = (f32x4){0.f, 0.f, 0.f, 0.f};
    }
    f32x4 ls0 = (f32x4){0.f, 0.f, 0.f, 0.f};
    f32x4 ls1 = (f32x4){0.f, 0.f, 0.f, 0.f};

    // ---- preload first owned K tile (in-bounds even when hf >= nk)
    bf16x8 ka[4], kb[4];
#pragma unroll
    for (int nt = 0; nt < 4; ++nt) {
        const size_t o = (((size_t)hf * 4 + nt) * 2) * 512;
        ka[nt] = load8(Kp + o + lane * 8);
        kb[nt] = load8(Kp + o + 512 + lane * 8);
    }

    for (int kt = hf; kt < nk; kt += 2) {
        // ---- V(kt) loads issued first: latency covered by both score passes
        bf16x8 va[4], vb[4];
#pragma unroll
        for (int nt = 0; nt < 4; ++nt) {
            const size_t o = (((size_t)kt * 4 + nt) * 2) * 512;
            va[nt] = load8(Vp + o + lane * 8);
            vb[nt] = load8(Vp + o + 512 + lane * 8);
        }
        // ---- K(kt+2) prefetch (redundant reload on last iter)
        const int nkt = (kt + 2 < nk) ? kt + 2 : kt;
        bf16x8 na[4], nb[4];
#pragma unroll
        for (int nt = 0; nt < 4; ++nt) {
            const size_t o = (((size_t)nkt * 4 + nt) * 2) * 512;
            na[nt] = load8(Kp + o + lane * 8);
            nb[nt] = load8(Kp + o + 512 + lane * 8);
        }

        const int kbase = kt * 64;
        const bool diag = (kt == nk - 1);

        // ---- tile 0: S^T = K·Q^T with -M2 folded into the accumulator init
        f32x4 sc[4];
#pragma unroll
        for (int ntk = 0; ntk < 4; ++ntk) {
            f32x4 z = (f32x4){-FIXED_M2, -FIXED_M2, -FIXED_M2, -FIXED_M2};
            z = MFMA16(ka[ntk], q0a, z);
            z = MFMA16(kb[ntk], q0b, z);
            sc[ntk] = z;
        }
        if (diag) {
            const int qrow = t0 * 16 + l16;
#pragma unroll
            for (int ntk = 0; ntk < 4; ++ntk)
#pragma unroll
                for (int r = 0; r < 4; ++r)
                    if (kbase + ntk * 16 + quad * 4 + r > qrow) sc[ntk][r] = -1e30f;
        }
#pragma unroll
        for (int ntk = 0; ntk < 4; ++ntk) {
            *reinterpret_cast<ushort4*>(&P[hf][0][l16 * 72 + ntk * 16 + quad * 4]) =
                pack4(fast_exp2(sc[ntk][0]), fast_exp2(sc[ntk][1]),
                      fast_exp2(sc[ntk][2]), fast_exp2(sc[ntk][3]));
        }

        // ---- tile 1 scores (last use of ka/kb)
#pragma unroll
        for (int ntk = 0; ntk < 4; ++ntk) {
            f32x4 z = (f32x4){-FIXED_M2, -FIXED_M2, -FIXED_M2, -FIXED_M2};
            z = MFMA16(ka[ntk], q1a, z);
            z = MFMA16(kb[ntk], q1b, z);
            sc[ntk] = z;
        }
        if (diag) {
            const int qrow = t1 * 16 + l16;
#pragma unroll
            for (int ntk = 0; ntk < 4; ++ntk)
#pragma unroll
                for (int r = 0; r < 4; ++r)
                    if (kbase + ntk * 16 + quad * 4 + r > qrow) sc[ntk][r] = -1e30f;
        }
#pragma unroll
        for (int ntk = 0; ntk < 4; ++ntk) {
            *reinterpret_cast<ushort4*>(&P[hf][1][l16 * 72 + ntk * 16 + quad * 4]) =
                pack4(fast_exp2(sc[ntk][0]), fast_exp2(sc[ntk][1]),
                      fast_exp2(sc[ntk][2]), fast_exp2(sc[ntk][3]));
        }

        // ---- PV tile 0: O^T += Vt · P^T ; row sums via ones-MFMA
        {
            bf16x8 pf0 = load8(&P[hf][0][l16 * 72 + quad * 8]);
            bf16x8 pf1 = load8(&P[hf][0][l16 * 72 + quad * 8 + 32]);
#pragma unroll
            for (int nt = 0; nt < 4; ++nt) {
                oa0[nt] = MFMA16(va[nt], pf0, oa0[nt]);
                oa0[nt] = MFMA16(vb[nt], pf1, oa0[nt]);
            }
            ls0 = MFMA16(onesf, pf0, ls0);
            ls0 = MFMA16(onesf, pf1, ls0);
        }
        // ---- PV tile 1
        {
            bf16x8 pf0 = load8(&P[hf][1][l16 * 72 + quad * 8]);
            bf16x8 pf1 = load8(&P[hf][1][l16 * 72 + quad * 8 + 32]);
#pragma unroll
            for (int nt = 0; nt < 4; ++nt) {
                oa1[nt] = MFMA16(va[nt], pf0, oa1[nt]);
                oa1[nt] = MFMA16(vb[nt], pf1, oa1[nt]);
            }
            ls1 = MFMA16(onesf, pf0, ls1);
            ls1 = MFMA16(onesf, pf1, ls1);
        }

        // ---- rotate K prefetch into place
#pragma unroll
        for (int nt = 0; nt < 4; ++nt) { ka[nt] = na[nt]; kb[nt] = nb[nt]; }
    }

    // ---- split-K combine across the 2 waves
    if (hf == 1) {
#pragma unroll
        for (int nt = 0; nt < 4; ++nt) {
            *reinterpret_cast<float4*>(&OB[0][l16 * 68 + nt * 16 + quad * 4]) =
                (float4){ oa0[nt][0], oa0[nt][1], oa0[nt][2], oa0[nt][3] };
            *reinterpret_cast<float4*>(&OB[1][l16 * 68 + nt * 16 + quad * 4]) =
                (float4){ oa1[nt][0], oa1[nt][1], oa1[nt][2], oa1[nt][3] };
        }
        if (quad == 0) { LB[0][l16] = ls0[0]; LB[1][l16] = ls1[0]; }
    }
    __syncthreads();
    if (hf == 0) {
#pragma unroll
        for (int tl = 0; tl < 2; ++tl) {
            const float lsw = (tl == 0) ? ls0[0] : ls1[0];
            const float inv = 1.0f / (lsw + LB[tl][l16]);
            const int rt = b * 128 + (tl == 0 ? t0 : t1);
#pragma unroll
            for (int nt = 0; nt < 4; ++nt) {
                float4 ob = *reinterpret_cast<float4*>(&OB[tl][l16 * 68 + nt * 16 + quad * 4]);
                const f32x4 ov = (tl == 0) ? oa0[nt] : oa1[nt];
                // e = h*64 + nt*16 + quad*4 + r  ->  A-frag order for out_proj
                const int kk     = h * 2 + (nt >> 1);
                const int quad_f = (nt & 1) * 2 + (quad >> 1);
                const int j0     = (quad & 1) * 4;
                *reinterpret_cast<ushort4*>(
                    Af + (((size_t)rt * 32 + kk) * 64 + quad_f * 16 + l16) * 8 + j0) =
                    pack4((ov[0] + ob.x) * inv, (ov[1] + ob.y) * inv,
                          (ov[2] + ob.z) * inv, (ov[3] + ob.w) * inv);
            }
        }
    }
}

// ---------------------------------------------------------------------------
// Kernel 3: out = att @ Wo.T + bo (fp32 out). Fragment-order A (Af) and B
// (Wf). 128x64 tile, prefetch depth 2 (12 loads in flight — verified best;
// depth 4 regressed, R5/R6). XCD-locality swizzle (neutral but free, R8).
// ---------------------------------------------------------------------------
__global__ __launch_bounds__(256) void out_proj(
    const __hip_bfloat16* __restrict__ Af,  // [rt][kk][lane][8]
    const __hip_bfloat16* __restrict__ Wf,  // [ct][kk][lane][8]
    const float* __restrict__ bo,           // [E] fp32
    float* __restrict__ out)                // [B*S, E] fp32
{
    const int bid = blockIdx.x;
    const int xcd = bid & 7;                // dispatch round-robins bid%8 -> XCD
    const int j   = bid >> 3;               // 0..63
    const int rb  = xcd * 4 + (j & 3);      // row block 0..31 (4096/128)
    const int cb  = j >> 2;                 // col tile 0..15 (E/64)
    const int tid = threadIdx.x, lane = tid & 63, w = tid >> 6;
    const int quad = lane >> 4, l16 = lane & 15;
    const int rt0 = rb * 8 + w;     // 16-row tiles; second at +4
    const int cbase = cb * 64;

    const __hip_bfloat16* pa0 = Af + ((size_t)rt0 * 32) * 512 + lane * 8;
    const __hip_bfloat16* pa1 = pa0 + 4 * 32 * 512;
    const __hip_bfloat16* pw  = Wf + ((size_t)cb * 4 * 32) * 512 + lane * 8;

    f32x4 acc[2][4];
#pragma unroll
    for (int u = 0; u < 2; ++u)
#pragma unroll
        for (int nt = 0; nt < 4; ++nt) acc[u][nt] = (f32x4){0.f, 0.f, 0.f, 0.f};

    // two fragment sets in flight (prefetch depth 2)
    bf16x8 af0[2], af1[2], bf[4][2];
#pragma unroll
    for (int s = 0; s < 2; ++s) {
        const size_t ko = (size_t)s * 512;
        af0[s] = load8(pa0 + ko);
        af1[s] = load8(pa1 + ko);
#pragma unroll
        for (int nt = 0; nt < 4; ++nt) bf[nt][s] = load8(pw + (size_t)nt * 32 * 512 + ko);
    }

    for (int kk = 0; kk < 32; kk += 2) {
#pragma unroll
        for (int s = 0; s < 2; ++s) {
            const int kn = kk + 2 + s;
            const size_t ko = (size_t)((kn < 32) ? kn : kk + s) * 512;
            bf16x8 naf0 = load8(pa0 + ko), naf1 = load8(pa1 + ko);
            bf16x8 nbf[4];
#pragma unroll
            for (int nt = 0; nt < 4; ++nt) nbf[nt] = load8(pw + (size_t)nt * 32 * 512 + ko);
#pragma unroll
            for (int nt = 0; nt < 4; ++nt) {
                acc[0][nt] = MFMA16(af0[s], bf[nt][s], acc[0][nt]);
                acc[1][nt] = MFMA16(af1[s], bf[nt][s], acc[1][nt]);
            }
            af0[s] = naf0; af1[s] = naf1;
#pragma unroll
            for (int nt = 0; nt < 4; ++nt) bf[nt][s] = nbf[nt];
        }
    }
#pragma unroll
    for (int nt = 0; nt < 4; ++nt) {
        const float bv = bo[cbase + nt * 16 + l16];
#pragma unroll
        for (int u = 0; u < 2; ++u)
#pragma unroll
            for (int r = 0; r < 4; ++r) {
                const int row = (rt0 + u * 4) * 16 + quad * 4 + r;
                out[(size_t)row * E + cbase + nt * 16 + l16] = acc[u][nt][r] + bv;
            }
    }
}

// ---------------------------------------------------------------------------
extern "C" void kernel_launch(void* const* d_in, const int* in_sizes, int n_in,
                              void* d_out, int out_size, void* d_ws, size_t ws_size,
                              hipStream_t stream) {
    const float* vals = (const float*)d_in[0];
    const float* keys = (const float*)d_in[1];
    const float* quer = (const float*)d_in[2];
    // d_in[3] = causal mask (bool): recomputed from indices, unused
    const float* Wv = (const float*)d_in[4];
    const float* Wk = (const float*)d_in[5];
    const float* Wq = (const float*)d_in[6];
    const float* Wo = (const float*)d_in[7];
    const float* bo = (const float*)d_in[8];
    float* out = (float*)d_out;

    __hip_bfloat16* ws = (__hip_bfloat16*)d_ws;
    constexpr size_t NTOK = (size_t)Bc * Hn * Sc * Dh;  // 4194304
    __hip_bfloat16* Qw  = ws;                 // 8 MB, fragment order
    __hip_bfloat16* Kw  = ws + NTOK;          // 8 MB, fragment order
    __hip_bfloat16* Vw  = ws + 2 * NTOK;      // 8 MB, fragment order
    __hip_bfloat16* Aw  = ws + 3 * NTOK;      // 8 MB, fragment order
    __hip_bfloat16* Wof = ws + 4 * NTOK;      // 2 MB, fragment order
    __hip_bfloat16* Wf3 = Wof + (size_t)E * E; // 24 KB, qkv W fragments

    hipLaunchKernelGGL(cvt_w, dim3(518), dim3(256), 0, stream, Wo, Wq, Wk, Wv, Wof, Wf3);
    hipLaunchKernelGGL(qkv_proj, dim3(Bc * Hn * (Sc / 64)), dim3(256), 0, stream,
                       vals, keys, quer, Wf3, Qw, Kw, Vw);
    hipLaunchKernelGGL(flash_attn, dim3(64 * 32), dim3(128), 0, stream,
                       Qw, Kw, Vw, Aw);
    hipLaunchKernelGGL(out_proj, dim3(32 * 16), dim3(256), 0, stream,
                       Aw, Wof, bo, out);
}